// Round 13
// baseline (265.683 us; speedup 1.0000x reference)
//
#include <hip/hip_runtime.h>
#include <hip/hip_bf16.h>
#include <math.h>

// Problem constants
#define BATCH 4
#define SEQ   2048
#define CDIM  1024
#define NHEAD 16
#define HDIM  64
#define QKVN  3072
#define QSCALE 0.1803368801111244f   // 0.125 * log2(e); softmax done in exp2 domain

typedef float f32x4 __attribute__((ext_vector_type(4)));
typedef float f32x16 __attribute__((ext_vector_type(16)));
typedef short bf16x8 __attribute__((ext_vector_type(8)));
typedef short bf16x4 __attribute__((ext_vector_type(4)));
typedef int i32x2 __attribute__((ext_vector_type(2)));
typedef int i32x4 __attribute__((ext_vector_type(4)));

static __device__ __forceinline__ unsigned short f2bf(float f) {
    unsigned int u = __float_as_uint(f);
    u += 0x7FFF + ((u >> 16) & 1);   // RNE
    return (unsigned short)(u >> 16);
}
static __device__ __forceinline__ float bf2f(unsigned short u) {
    return __uint_as_float(((unsigned int)u) << 16);
}
static __device__ __forceinline__ unsigned int pk2bf(float lo, float hi) {
    __hip_bfloat162 h = __float22bfloat162_rn(make_float2(lo, hi));
    return *(unsigned int*)&h;
}

// ---------------- consolidated prep: ctab + x->bf16 + both W transposes ------
static __device__ __forceinline__ void transpose_tile(
    const float* __restrict__ W, unsigned short* __restrict__ Wt,
    int K, int N, int bx, int by, unsigned short (*tile)[65], int tid) {
    const int n0 = bx * 64;
    const int k0 = by * 64;
    const int r = tid >> 4;
    const int c4 = (tid & 15) << 2;
    #pragma unroll
    for (int ii = 0; ii < 4; ii++) {
        int row = r + 16 * ii;
        float4 v = *(const float4*)&W[(size_t)(k0 + row) * N + n0 + c4];
        tile[c4 + 0][row] = f2bf(v.x);
        tile[c4 + 1][row] = f2bf(v.y);
        tile[c4 + 2][row] = f2bf(v.z);
        tile[c4 + 3][row] = f2bf(v.w);
    }
    __syncthreads();
    #pragma unroll
    for (int ii = 0; ii < 4; ii++) {
        int row = r + 16 * ii;
        ushort4 o;
        o.x = tile[row][c4 + 0];
        o.y = tile[row][c4 + 1];
        o.z = tile[row][c4 + 2];
        o.w = tile[row][c4 + 3];
        *(ushort4*)&Wt[(size_t)(n0 + row) * K + k0 + c4] = o;
    }
}

__global__ __launch_bounds__(256) void prep(
    const float* __restrict__ x, const float* __restrict__ W_qkv,
    const float* __restrict__ W_out, float2* __restrict__ ctab,
    unsigned short* __restrict__ xb, unsigned short* __restrict__ wqb,
    unsigned short* __restrict__ wob) {
    __shared__ unsigned short tile[64][65];
    const int blk = blockIdx.x;
    const int tid = threadIdx.x;
    if (blk < 8192) {
        // x fp32 -> xb bf16, 2,097,152 float4s
        const int i = blk * 256 + tid;
        float4 v = ((const float4*)x)[i];
        ushort4 o;
        o.x = f2bf(v.x); o.y = f2bf(v.y); o.z = f2bf(v.z); o.w = f2bf(v.w);
        ((ushort4*)xb)[i] = o;
    } else if (blk < 8448) {
        // RoPE table: ctab[t*32+dp] = (cos, sin), 65536 entries
        const int i = (blk - 8192) * 256 + tid;
        const int dp = i & 31;
        const int t = i >> 5;
        const float invf = powf(10000.0f, -((float)(2 * dp)) / 64.0f);
        float sv, cv;
        __sincosf((float)t * invf, &sv, &cv);
        ctab[i] = make_float2(cv, sv);
    } else if (blk < 9216) {
        // W_qkv [1024][3072] -> wqb [3072][1024], dim3(48,16)
        const int r = blk - 8448;
        transpose_tile(W_qkv, wqb, CDIM, QKVN, r % 48, r / 48, tile, tid);
    } else {
        // W_out [1024][1024] -> wob [1024][1024]^T, dim3(16,16)
        const int r = blk - 9216;
        transpose_tile(W_out, wob, CDIM, CDIM, r % 16, r / 16, tile, tid);
    }
}

#define GLDS(gp, lp) __builtin_amdgcn_global_load_lds(                       \
    (const __attribute__((address_space(1))) unsigned int*)(gp),             \
    (__attribute__((address_space(3))) unsigned int*)(lp), 16, 0, 0)

// ---------------- bf16 MFMA GEMM, BK=64 + pinned occupancy (R11/R12 proven) --
template <typename OUT>
__global__ __launch_bounds__(256, 4) void gemm_bt_bf16(
    const unsigned short* __restrict__ A,
    const unsigned short* __restrict__ Bt,
    OUT* __restrict__ C, int M, int N, int K) {
    __shared__ unsigned short As[128 * 64];
    __shared__ unsigned short Bs[128 * 64];

    const int tid = threadIdx.x;
    const int wave = tid >> 6;
    const int lane = tid & 63;
    const int bm = blockIdx.y * 128;
    const int bn = blockIdx.x * 128;
    const int wm = (wave >> 1) * 64;
    const int wn = (wave & 1) * 64;

    const int sr = tid >> 3;
    const int sc = ((tid & 7) ^ (sr & 7)) << 3;
    const unsigned short* Ag = A + (size_t)(bm + sr) * K + sc;
    const unsigned short* Bg = Bt + (size_t)(bn + sr) * K + sc;
    char* AsW = (char*)As + wave * 1024;
    char* BsW = (char*)Bs + wave * 1024;

    const int fm = lane & 15;
    const int quad = lane >> 4;
    const int sl0 = ((quad ^ (fm & 7)) << 3);        // ks=0 slot (elem offset)
    const int sl1 = (((4 + quad) ^ (fm & 7)) << 3);  // ks=1 slot

    f32x4 acc[4][4];
    #pragma unroll
    for (int i = 0; i < 4; i++)
        #pragma unroll
        for (int j = 0; j < 4; j++)
            acc[i][j] = (f32x4){0.f, 0.f, 0.f, 0.f};

    for (int k0 = 0; k0 < K; k0 += 64) {
        GLDS(Ag + k0, AsW);
        GLDS(Ag + 32 * K + k0, AsW + 4096);
        GLDS(Ag + 64 * K + k0, AsW + 8192);
        GLDS(Ag + 96 * K + k0, AsW + 12288);
        GLDS(Bg + k0, BsW);
        GLDS(Bg + 32 * K + k0, BsW + 4096);
        GLDS(Bg + 64 * K + k0, BsW + 8192);
        GLDS(Bg + 96 * K + k0, BsW + 12288);
        __syncthreads();

        bf16x8 af[4], bfr[4];
        // ---- ks = 0 slice ----
        #pragma unroll
        for (int i = 0; i < 4; i++)
            af[i] = *(const bf16x8*)&As[(wm + i * 16 + fm) * 64 + sl0];
        #pragma unroll
        for (int j = 0; j < 4; j++)
            bfr[j] = *(const bf16x8*)&Bs[(wn + j * 16 + fm) * 64 + sl0];
        #pragma unroll
        for (int i = 0; i < 4; i++)
            #pragma unroll
            for (int j = 0; j < 4; j++)
                acc[i][j] = __builtin_amdgcn_mfma_f32_16x16x32_bf16(
                    af[i], bfr[j], acc[i][j], 0, 0, 0);
        // ---- ks = 1 slice ----
        #pragma unroll
        for (int i = 0; i < 4; i++)
            af[i] = *(const bf16x8*)&As[(wm + i * 16 + fm) * 64 + sl1];
        #pragma unroll
        for (int j = 0; j < 4; j++)
            bfr[j] = *(const bf16x8*)&Bs[(wn + j * 16 + fm) * 64 + sl1];
        #pragma unroll
        for (int i = 0; i < 4; i++)
            #pragma unroll
            for (int j = 0; j < 4; j++)
                acc[i][j] = __builtin_amdgcn_mfma_f32_16x16x32_bf16(
                    af[i], bfr[j], acc[i][j], 0, 0, 0);
        __syncthreads();
    }

    const int er = quad * 4;
    #pragma unroll
    for (int i = 0; i < 4; i++) {
        #pragma unroll
        for (int j = 0; j < 4; j++) {
            #pragma unroll
            for (int r = 0; r < 4; r++) {
                size_t off = (size_t)(bm + wm + i * 16 + er + r) * N + bn + wn + j * 16 + fm;
                if constexpr (sizeof(OUT) == 2)
                    C[off] = f2bf(acc[i][j][r]);
                else
                    C[off] = acc[i][j][r];
            }
        }
    }
}

// ---------------- fused qkv GEMM, BK=64 + pinned occupancy (R11, proven) -----
__global__ __launch_bounds__(256, 4) void gemm_qkv_fused(
    const unsigned short* __restrict__ A,     // xb [8192][1024]
    const unsigned short* __restrict__ Bt,    // wqb [3072][1024]
    const float2* __restrict__ ctab,          // [2048][32]
    unsigned short* __restrict__ Qg,
    unsigned short* __restrict__ Kg,
    unsigned short* __restrict__ Vtg) {
    __shared__ unsigned short SH[16384];      // loop: As=SH[0:8192), Bs=SH[8192:16384)
                                              // epilogue: [64][132] bf16 tile
    unsigned short* As = SH;
    unsigned short* Bs = SH + 8192;
    const int K = CDIM;

    const int tid = threadIdx.x;
    const int wave = tid >> 6;
    const int lane = tid & 63;
    const int bm = blockIdx.y * 128;
    const int bn = blockIdx.x * 128;
    const int wm = (wave >> 1) * 64;
    const int wn = (wave & 1) * 64;

    const int sr = tid >> 3;
    const int sc = ((tid & 7) ^ (sr & 7)) << 3;
    const unsigned short* Ag = A + (size_t)(bm + sr) * K + sc;
    const unsigned short* Bg = Bt + (size_t)(bn + sr) * K + sc;
    char* AsW = (char*)SH + wave * 1024;
    char* BsW = (char*)SH + 16384 + wave * 1024;   // byte offset of Bs

    const int fm = lane & 15;
    const int quad = lane >> 4;
    const int sl0 = ((quad ^ (fm & 7)) << 3);
    const int sl1 = (((4 + quad) ^ (fm & 7)) << 3);

    f32x4 acc[4][4];
    #pragma unroll
    for (int i = 0; i < 4; i++)
        #pragma unroll
        for (int j = 0; j < 4; j++)
            acc[i][j] = (f32x4){0.f, 0.f, 0.f, 0.f};

    for (int k0 = 0; k0 < K; k0 += 64) {
        GLDS(Ag + k0, AsW);
        GLDS(Ag + 32 * K + k0, AsW + 4096);
        GLDS(Ag + 64 * K + k0, AsW + 8192);
        GLDS(Ag + 96 * K + k0, AsW + 12288);
        GLDS(Bg + k0, BsW);
        GLDS(Bg + 32 * K + k0, BsW + 4096);
        GLDS(Bg + 64 * K + k0, BsW + 8192);
        GLDS(Bg + 96 * K + k0, BsW + 12288);
        __syncthreads();

        bf16x8 af[4], bfr[4];
        // ---- ks = 0 slice ----
        #pragma unroll
        for (int i = 0; i < 4; i++)
            af[i] = *(const bf16x8*)&As[(wm + i * 16 + fm) * 64 + sl0];
        #pragma unroll
        for (int j = 0; j < 4; j++)
            bfr[j] = *(const bf16x8*)&Bs[(wn + j * 16 + fm) * 64 + sl0];
        #pragma unroll
        for (int i = 0; i < 4; i++)
            #pragma unroll
            for (int j = 0; j < 4; j++)
                acc[i][j] = __builtin_amdgcn_mfma_f32_16x16x32_bf16(
                    af[i], bfr[j], acc[i][j], 0, 0, 0);
        // ---- ks = 1 slice ----
        #pragma unroll
        for (int i = 0; i < 4; i++)
            af[i] = *(const bf16x8*)&As[(wm + i * 16 + fm) * 64 + sl1];
        #pragma unroll
        for (int j = 0; j < 4; j++)
            bfr[j] = *(const bf16x8*)&Bs[(wn + j * 16 + fm) * 64 + sl1];
        #pragma unroll
        for (int i = 0; i < 4; i++)
            #pragma unroll
            for (int j = 0; j < 4; j++)
                acc[i][j] = __builtin_amdgcn_mfma_f32_16x16x32_bf16(
                    af[i], bfr[j], acc[i][j], 0, 0, 0);
        __syncthreads();
    }

    // ---------------- fused epilogue (unchanged from R7/R9) ----------------
    const int s = bn >> 10;                  // 0=q, 1=k, 2=v (128-col tile never straddles)
    const int hbase = (bn & 1023) >> 6;      // block covers heads hbase, hbase+1
    const int b = bm >> 11;                  // 128-row tile never straddles batch
    const int t0 = bm & 2047;

    #pragma unroll 1
    for (int pass = 0; pass < 2; pass++) {
        // waves whose rows are in this half write their acc tile to SH [64][132]
        if ((wave >> 1) == pass) {
            #pragma unroll
            for (int i = 0; i < 4; i++)
                #pragma unroll
                for (int j = 0; j < 4; j++)
                    #pragma unroll
                    for (int r = 0; r < 4; r++)
                        SH[(i * 16 + quad * 4 + r) * 132 + wn + j * 16 + fm] =
                            f2bf(acc[i][j][r]);
        }
        __syncthreads();

        if (s < 2) {
            unsigned short* dst = (s == 0) ? Qg : Kg;
            const float sc2 = (s == 0) ? QSCALE : 1.0f;
            #pragma unroll
            for (int it = 0; it < 16; it++) {
                const int idx = it * 256 + tid;      // 64 rows x 64 col-pairs
                const int row = idx >> 6;
                const int col = (idx & 63) << 1;
                const unsigned int pr = *(const unsigned int*)&SH[row * 132 + col];
                const float x0 = bf2f((unsigned short)pr);
                const float x1 = bf2f((unsigned short)(pr >> 16));
                const int t = t0 + pass * 64 + row;
                const int h = hbase + (col >> 6);
                const int d = col & 63;
                const float2 cs = ctab[t * 32 + (d >> 1)];
                const float r0 = (x0 * cs.x - x1 * cs.y) * sc2;
                const float r1 = (x1 * cs.x + x0 * cs.y) * sc2;
                *(unsigned int*)&dst[((size_t)(b * NHEAD + h) * SEQ + t) * HDIM + d] =
                    pk2bf(r0, r1);
            }
        } else {
            #pragma unroll
            for (int it = 0; it < 8; it++) {
                const int idx = it * 256 + tid;      // 128 cols x 16 t-chunks
                const int dcol = idx >> 4;
                const int tq = idx & 15;
                ushort4 o;
                o.x = SH[(tq * 4 + 0) * 132 + dcol];
                o.y = SH[(tq * 4 + 1) * 132 + dcol];
                o.z = SH[(tq * 4 + 2) * 132 + dcol];
                o.w = SH[(tq * 4 + 3) * 132 + dcol];
                const int h = hbase + (dcol >> 6);
                const int dl = dcol & 63;
                const int t = t0 + pass * 64 + tq * 4;
                *(ushort4*)&Vtg[((size_t)(b * NHEAD + h) * HDIM + dl) * SEQ + t] = o;
            }
        }
        __syncthreads();
    }
}

// ---------------- MFMA flash attention: GLDS-staged K/V (R13) ----------------
// R12 post-mortem: removing VALU adds changed the mix (VALUBusy 59->57,
// MfmaUtil 19->23) but not the time -> issue stream still dominated by the
// reg-round-trip staging (8 global loads + 8 ds_writes + addr chains /
// thread / iter) and the pitch-68 lds_read8 b64 splits. R13 ports the
// GEMM's verified GLDS+swizzle staging: linear [64][64] tiles, global
// source chunk pre-swizzled cg=(t&7)^(r&7) (GLDS writes lane-contiguous,
// m104), reads at slot=(chunk)^(row&7) -> every 16B slot gets exactly 8
// lanes = 8 words/bank = minimum passes, 0 conflicts. Rows now 128B-aligned
// -> direct ds_read_b128. Dbuf 2-phase: GLDS for tile j+1 issued at iter
// top into the idle buffer; end-of-iter barrier's vmcnt(0) drains loads a
// full iteration old. Costs ZERO VGPRs (removes 16 staging regs) unlike
// R8's failed GEMM dbuf. LDS 34.8 -> 32KB.
__global__ __launch_bounds__(256, 4) void flash_attn_mfma(
    const unsigned short* __restrict__ Qg,
    const unsigned short* __restrict__ Kg,
    const unsigned short* __restrict__ Vtg,
    unsigned short* __restrict__ att) {
    __shared__ unsigned short Ks[2][64 * 64];   // [buf][key][d], chunk-swizzled
    __shared__ unsigned short Vt[2][64 * 64];   // [buf][d][key], chunk-swizzled

    const int tid = threadIdx.x;
    const int wave = tid >> 6;
    const int lane = tid & 63;
    const int l31 = lane & 31;
    const int hi = lane >> 5;
    const int wq = wave * 32;
    const int bh = blockIdx.x & 63;          // blk%8==bh%8 -> bh's blocks share an XCD
    const int qt = 15 - (blockIdx.x >> 6);   // heavy Q-tiles first
    const int b = bh >> 4, h = bh & 15;

    // GLDS staging: thread t covers row r=t>>3 (first 32 rows; +32 in call 2),
    // global 16B-chunk (t&7)^(r&7); LDS slot s of row r holds chunk s^(r&7).
    const int srow = tid >> 3;
    const int scg = ((tid & 7) ^ (srow & 7)) << 3;   // element offset of chunk
    const unsigned short* Ksrc = Kg + (size_t)bh * SEQ * HDIM + (size_t)srow * HDIM + scg;
    const unsigned short* Vsrc = Vtg + (size_t)bh * HDIM * SEQ + (size_t)srow * SEQ + scg;

    const int qrow = qt * 128 + wq + l31;    // this lane's q column
    const int x7 = (l31 & 7);                // read-side swizzle key

    // Q B-fragments (n=l31=q, k=d chunk dc*16 + hi*8): 4 x 16B from global
    bf16x8 bq[4];
    #pragma unroll
    for (int dc = 0; dc < 4; dc++)
        bq[dc] = *(const bf16x8*)&Qg[((size_t)bh * SEQ + qrow) * HDIM + dc * 16 + hi * 8];

    // bf16 1.0 broadcast B-operand for the row-sum MFMA
    bf16x8 bones;
    #pragma unroll
    for (int z = 0; z < 8; z++) bones[z] = (short)0x3F80;

    f32x16 O[2], lsum16;
    #pragma unroll
    for (int nt = 0; nt < 2; nt++)
        #pragma unroll
        for (int r = 0; r < 16; r++) O[nt][r] = 0.f;
    #pragma unroll
    for (int r = 0; r < 16; r++) lsum16[r] = 0.f;

    const int jtop = 2 * qt + 1;

    // ---- prologue: GLDS tile 0 into buffer 0 ----
    {
        char* kb = (char*)Ks[0] + wave * 1024;
        char* vb = (char*)Vt[0] + wave * 1024;
        GLDS(Ksrc, kb);                 GLDS(Ksrc + 32 * HDIM, kb + 4096);
        GLDS(Vsrc, vb);                 GLDS(Vsrc + 32 * SEQ, vb + 4096);
    }
    __syncthreads();

    int cur = 0;
    #pragma unroll 1
    for (int j = 0; j <= jtop; j++) {
        // (A) issue GLDS for tile j+1 into the idle buffer; the end-of-iter
        //     barrier's vmcnt(0) drains them a full compute phase later.
        //     Safe: buf cur^1's readers finished at the previous barrier.
        if (j < jtop) {
            char* kb = (char*)Ks[cur ^ 1] + wave * 1024;
            char* vb = (char*)Vt[cur ^ 1] + wave * 1024;
            const unsigned short* kjs = Ksrc + (size_t)(j + 1) * 64 * HDIM;
            const unsigned short* vjs = Vsrc + (j + 1) * 64;
            GLDS(kjs, kb);              GLDS(kjs + 32 * HDIM, kb + 4096);
            GLDS(vjs, vb);              GLDS(vjs + 32 * SEQ, vb + 4096);
        }

        // (B) compute tile j from buffer cur
        const bool active = (j * 64) <= (qt * 128 + wq + 31);
        if (active) {
            const unsigned short* Kc = Ks[cur];
            const unsigned short* Vc = Vt[cur];
            const bool diag = (j * 64 + 63) > (qt * 128 + wq);

            #pragma unroll
            for (int kt = 0; kt < 2; kt++) {
                // ---- S^T = K Q^T : D[k][q], lane col q=l31 ----
                f32x16 sa;
                #pragma unroll
                for (int r = 0; r < 16; r++) sa[r] = 0.f;
                __builtin_amdgcn_s_setprio(1);
                #pragma unroll
                for (int dc = 0; dc < 4; dc++) {
                    bf16x8 ak = *(const bf16x8*)&Kc[(kt * 32 + l31) * 64 +
                                                    (((dc * 2 + hi) ^ x7) << 3)];
                    sa = __builtin_amdgcn_mfma_f32_32x32x16_bf16(ak, bq[dc], sa, 0, 0, 0);
                }
                __builtin_amdgcn_s_setprio(0);

                // ---- causal mask (diagonal tiles only): k_glob > q ----
                if (diag) {
                    const int kb = j * 64 + kt * 32 + 4 * hi;
                    #pragma unroll
                    for (int r = 0; r < 16; r++) {
                        const int kg = kb + (r & 3) + 8 * (r >> 2);
                        if (kg > qrow) sa[r] = -INFINITY;
                    }
                }

                // ---- P = exp2(S) packed straight to bf16 ----
                unsigned int p32[8];
                #pragma unroll
                for (int v = 0; v < 8; v++)
                    p32[v] = pk2bf(exp2f(sa[2 * v]), exp2f(sa[2 * v + 1]));

                // ---- permlane32_swap -> PV A-frags; O += P@V; l += P@1 ----
                #pragma unroll
                for (int c = 0; c < 2; c++) {
                    i32x2 s0 = __builtin_amdgcn_permlane32_swap(
                        (int)p32[4 * c + 0], (int)p32[4 * c + 2], false, false);
                    i32x2 s1 = __builtin_amdgcn_permlane32_swap(
                        (int)p32[4 * c + 1], (int)p32[4 * c + 3], false, false);
                    i32x4 pw = (i32x4){s0[0], s1[0], s0[1], s1[1]};
                    bf16x8 pa = *(bf16x8*)&pw;
                    __builtin_amdgcn_s_setprio(1);
                    lsum16 = __builtin_amdgcn_mfma_f32_32x32x16_bf16(pa, bones, lsum16, 0, 0, 0);
                    #pragma unroll
                    for (int nt = 0; nt < 2; nt++) {
                        bf16x8 bv = *(const bf16x8*)&Vc[(nt * 32 + l31) * 64 +
                                                        (((kt * 4 + c * 2 + hi) ^ x7) << 3)];
                        O[nt] = __builtin_amdgcn_mfma_f32_32x32x16_bf16(pa, bv, O[nt], 0, 0, 0);
                    }
                    __builtin_amdgcn_s_setprio(0);
                }
            }
        }

        // (C) one barrier per iteration: drains tile j+1's GLDS (vmcnt(0)
        //     before s_barrier) and closes all reads of buf cur.
        __syncthreads();
        cur ^= 1;
    }

    // ---- epilogue: lsum16 rows == O rows -> per-register normalize, store ----
    #pragma unroll
    for (int r = 0; r < 16; r++) {
        const float inv = 1.0f / lsum16[r];
        const int qloc = (r & 3) + 8 * (r >> 2) + 4 * hi;   // O row within 32
        const int row = qt * 128 + wq + qloc;
        #pragma unroll
        for (int nt = 0; nt < 2; nt++)
            att[(size_t)(b * SEQ + row) * CDIM + h * HDIM + nt * 32 + l31] =
                f2bf(O[nt][r] * inv);
    }
}

extern "C" void kernel_launch(void* const* d_in, const int* in_sizes, int n_in,
                              void* d_out, int out_size, void* d_ws, size_t ws_size,
                              hipStream_t stream) {
    const float* x     = (const float*)d_in[0];
    const float* W_qkv = (const float*)d_in[1];
    const float* W_out = (const float*)d_in[2];
    float* out = (float*)d_out;

    const int M = BATCH * SEQ;   // 8192

    // workspace layout (~92 MB)
    float2* ctab = (float2*)d_ws;                               // 2048*32 float2
    unsigned short* xb   = (unsigned short*)(ctab + SEQ * 32);  // M*1024 bf16
    unsigned short* wqb  = xb + (size_t)M * CDIM;               // 3072*1024
    unsigned short* wob  = wqb + (size_t)CDIM * QKVN;           // 1024*1024
    unsigned short* attb = wob + (size_t)CDIM * CDIM;           // M*1024
    unsigned short* Qg   = attb + (size_t)M * CDIM;             // [bh][t][d]
    unsigned short* Kg   = Qg + (size_t)M * CDIM;
    unsigned short* Vtg  = Kg + (size_t)M * CDIM;               // [bh][d][t]

    // 1) consolidated prep: ctab + x->bf16 + W transposes (one launch)
    prep<<<9472, 256, 0, stream>>>(x, W_qkv, W_out, ctab, xb, wqb, wob);

    // 2) fused qkv GEMM (BK=64, occupancy-pinned, R11-proven): writes Qg/Kg/Vtg
    gemm_qkv_fused<<<dim3(QKVN / 128, M / 128), 256, 0, stream>>>(
        xb, wqb, ctab, Qg, Kg, Vtg);

    // 3) MFMA flash attention: GLDS-staged K/V + in-register P (R13)
    flash_attn_mfma<<<BATCH * NHEAD * (SEQ / 128), 256, 0, stream>>>(Qg, Kg, Vtg, attb);

    // 4) out = att @ W_out (BK=64, occupancy-pinned, fp32 out)
    gemm_bt_bf16<float><<<dim3(CDIM / 128, M / 128), 256, 0, stream>>>(
        attb, wob, out, M, CDIM, CDIM);
}